// Round 13
// baseline (506.706 us; speedup 1.0000x reference)
//
#include <hip/hip_runtime.h>
#include <hip/hip_bf16.h>

typedef __attribute__((ext_vector_type(8))) short bf16x8;
typedef __attribute__((ext_vector_type(4))) float f32x4;

__device__ __forceinline__ unsigned short f2bf(float f){
  __hip_bfloat16 h = __float2bfloat16(f);
  return *reinterpret_cast<unsigned short*>(&h);
}

#define GLDS16(gptr, lptr) \
  __builtin_amdgcn_global_load_lds((const __attribute__((address_space(1))) unsigned int*)(gptr), \
                                   (__attribute__((address_space(3))) unsigned int*)(lptr), 16, 0, 0)

// ---------------- merged prep: qkv weight cast (blocks 0..767) + combo build (768..3903) ----------------
__global__ void prepk(const float* __restrict__ qkvw, unsigned short* __restrict__ wq,
                      const int* __restrict__ ri, const float* __restrict__ tbl,
                      const float* __restrict__ mask, unsigned short* __restrict__ combo){
  int blk = blockIdx.x;
  if (blk < 768){
    int i = blk*256 + threadIdx.x;
    wq[i] = f2bf(qkvw[i]);
    return;
  }
  int g = (blk - 768)*256 + threadIdx.x;
  if (g >= 802816) return;
  int r = g & 3;
  int t = g >> 2;
  int lane = t & 63; t >>= 6;
  int nt = t % 7; t /= 7;
  int mt = t % 7; t /= 7;
  int p = t >> 3, h = t & 7;
  int gi = mt*16 + (lane >> 4)*4 + r; if (gi > 97) gi = 97;
  int j  = nt*16 + (lane & 15);
  float v;
  if (j < 98){
    int wrep = ((p&4)?448:0) + ((p&2)?56:0) + ((p&1)?7:0);
    v = tbl[ri[gi*98 + j]*8 + h] + mask[(size_t)wrep*9604 + gi*98 + j];
  } else {
    v = -30000.f;
  }
  combo[g] = f2bf(v);
}

// two-source conversion (w1 then w2 into adjacent dests)
__global__ void cvt2k(const float* __restrict__ s1, int n1, const float* __restrict__ s2, int n2,
                      unsigned short* __restrict__ d){
  int i = blockIdx.x*256 + threadIdx.x;
  if (i < n1) d[i] = f2bf(s1[i]);
  else if (i < n1 + n2) d[i] = f2bf(s2[i - n1]);
}

__global__ void cvtk(const float* __restrict__ s, unsigned short* __restrict__ d, int n){
  int i = blockIdx.x*256 + threadIdx.x;
  if (i < n) d[i] = f2bf(s[i]);
}

// ---------------- LayerNorm (+optional shift/window map) ----------------
__launch_bounds__(256)
__global__ void lnk(const float* __restrict__ xin, const float* __restrict__ gw, const float* __restrict__ gb,
                    unsigned short* __restrict__ hout, int mode)
{
  int wid = threadIdx.x >> 6, lane = threadIdx.x & 63;
  int tok = blockIdx.x*4 + wid;
  int src;
  if (mode == 0){
    int w = tok / 98, n = tok % 98;
    int b = w >> 9, rr = w & 511;
    int di = rr >> 6, hi = (rr >> 3) & 7, wi = rr & 7;
    int d2 = n / 49, n2 = n % 49, h2 = n2 / 7, w2 = n2 % 7;
    int sd = (di*2 + d2 + 1) & 15;
    int sh = hi*7 + h2 + 3; if (sh >= 56) sh -= 56;
    int sw = wi*7 + w2 + 3; if (sw >= 56) sw -= 56;
    src = ((b*16 + sd)*56 + sh)*56 + sw;
  } else {
    src = tok;
  }
  float4 v = *(const float4*)(xin + (size_t)src*256 + lane*4);
  float s  = v.x + v.y + v.z + v.w;
  float s2 = v.x*v.x + v.y*v.y + v.z*v.z + v.w*v.w;
  #pragma unroll
  for (int off = 1; off < 64; off <<= 1){
    s  += __shfl_xor(s, off);
    s2 += __shfl_xor(s2, off);
  }
  float mean = s * (1.f/256.f);
  float var  = s2 * (1.f/256.f) - mean*mean;
  float rstd = rsqrtf(var + 1e-5f);
  int c = lane*4;
  float4 wv = *(const float4*)(gw + c);
  float4 bv = *(const float4*)(gb + c);
  unsigned int p0 = (unsigned int)f2bf((v.x-mean)*rstd*wv.x + bv.x)
                  | ((unsigned int)f2bf((v.y-mean)*rstd*wv.y + bv.y) << 16);
  unsigned int p1 = (unsigned int)f2bf((v.z-mean)*rstd*wv.z + bv.z)
                  | ((unsigned int)f2bf((v.w-mean)*rstd*wv.w + bv.w) << 16);
  uint2 pk; pk.x = p0; pk.y = p1;
  *(uint2*)(hout + (size_t)tok*256 + c) = pk;
}

// ---------------- bf16 MFMA GEMM: C[M,N] = A[M,K] * Bw[N,K]^T + bias ----------------
// XCD-chunked bijective block swizzle; T2 LDS XOR-swizzle; TRI-BUFFER staging with
// prefetch distance 2 and counted vmcnt: loop issues tile t+2, waits vmcnt(8)
// (= only tile t's 4 oldest loads; tiles t+1,t+2 stay in flight across barriers).
// Tile t's loads get TWO compute phases of latency cover. LDS 48KB -> 3 blocks/CU.
// Race audit: WAR on buf (t+2)%3 protected by iteration t-1's closing barrier;
// RAW by per-thread vmcnt + barrier-1. B-row permutation -> each lane's 4 ni-values
// are 4 CONSECUTIVE output columns -> vectorized epilogues.
// NOTE: launch_bounds (256,3) — RELAXED vs (256,4); (256,5) spilled (round 11).
// EPI 0: qkv plain [row][768] (+q scale on cols<256)
// EPI 1: proj + unwindow/unroll + residual
// EPI 2: fc1 + GELU(erf) -> bf16           EPI 3: fc2 accumulate into d_out
template<int EPI>
__launch_bounds__(256, 3)
__global__ void gemmk(const unsigned short* __restrict__ A, const unsigned short* __restrict__ Bw,
                      const float* __restrict__ bias, int K, int nbx,
                      unsigned short* __restrict__ outb, const float* __restrict__ xres,
                      float* __restrict__ outf, int moff)
{
  __shared__ unsigned short As[3][4096];
  __shared__ unsigned short Bs[3][4096];
  int tid = threadIdx.x;
  int wid = tid >> 6, lane = tid & 63, l16 = lane & 15, lk = lane >> 4;
  int wm = wid >> 1, wn = wid & 1;
  int cpx = gridDim.x >> 3;
  int swb = (blockIdx.x & 7)*cpx + (blockIdx.x >> 3);
  int mblk = swb / nbx, nblk = swb % nbx;
  const unsigned short* Ab = A  + (size_t)mblk*128*K;
  const unsigned short* Bb = Bw + (size_t)nblk*128*K;
  int rA = tid >> 2;
  int rB = ((rA & 15) << 2) + ((rA >> 4) & 3);    // B-row permutation (within 64-half)
  int kcA = (((tid & 3) ^ ((tid >> 3) & 3)))*8;   // pre-swizzled global k-slot
  int sx = (l16 >> 1) & 3;                        // read-side XOR factor

#define STAGE(bufi, kss) do { \
    GLDS16(Ab + (size_t)rA*K      + (kss) + kcA, &As[bufi][wid*512]); \
    GLDS16(Ab + (size_t)(rA+64)*K + (kss) + kcA, &As[bufi][2048 + wid*512]); \
    GLDS16(Bb + (size_t)rB*K      + (kss) + kcA, &Bs[bufi][wid*512]); \
    GLDS16(Bb + (size_t)(rB+64)*K + (kss) + kcA, &Bs[bufi][2048 + wid*512]); \
  } while(0)

  f32x4 acc[4][4];
  #pragma unroll
  for (int i = 0; i < 4; i++)
    #pragma unroll
    for (int j = 0; j < 4; j++)
      acc[i][j] = (f32x4){0.f,0.f,0.f,0.f};

  STAGE(0, 0);
  STAGE(1, 32);            // K >= 64 for every call site
  int cur = 0;
  for (int ks = 0; ks < K; ks += 32){
    int rem = K - ks;
    if (rem > 64){
      int b2 = (cur == 0) ? 2 : cur - 1;             // (cur+2)%3
      STAGE(b2, ks + 64);                            // prefetch tile t+2
      asm volatile("s_waitcnt vmcnt(8)" ::: "memory"); // tile t retired; t+1,t+2 in flight
    } else if (rem > 32){
      asm volatile("s_waitcnt vmcnt(4)" ::: "memory"); // tile t retired; t+1 in flight
    } else {
      asm volatile("s_waitcnt vmcnt(0)" ::: "memory");
    }
    __builtin_amdgcn_s_barrier();
    __builtin_amdgcn_sched_barrier(0);
    bf16x8 af[4], bfr[4];
    #pragma unroll
    for (int mi = 0; mi < 4; mi++) af[mi]  = *(const bf16x8*)&As[cur][(wm*64 + mi*16 + l16)*32 + (lk ^ sx)*8];
    #pragma unroll
    for (int ni = 0; ni < 4; ni++) bfr[ni] = *(const bf16x8*)&Bs[cur][(wn*64 + ni*16 + l16)*32 + (lk ^ sx)*8];
    #pragma unroll
    for (int mi = 0; mi < 4; mi++)
      #pragma unroll
      for (int ni = 0; ni < 4; ni++)
        acc[mi][ni] = __builtin_amdgcn_mfma_f32_16x16x32_bf16(af[mi], bfr[ni], acc[mi][ni], 0, 0, 0);
    __builtin_amdgcn_sched_barrier(0);
    __builtin_amdgcn_s_barrier();
    cur = (cur == 2) ? 0 : cur + 1;
  }
#undef STAGE

  int rowb = mblk*128 + wm*64;
  int colb = nblk*128 + wn*64;
  int c4 = colb + 4*l16;                 // this lane's 4 consecutive output columns
  float4 bv = *(const float4*)(bias + c4);
  #pragma unroll
  for (int mi = 0; mi < 4; mi++){
    #pragma unroll
    for (int r = 0; r < 4; r++){
      int row = rowb + mi*16 + lk*4 + r;
      float v0 = acc[mi][0][r] + bv.x;
      float v1 = acc[mi][1][r] + bv.y;
      float v2 = acc[mi][2][r] + bv.z;
      float v3 = acc[mi][3][r] + bv.w;
      if constexpr (EPI == 0){
        if (colb < 256){
          const float sc = 0.17677669529663687f;
          v0 *= sc; v1 *= sc; v2 *= sc; v3 *= sc;
        }
        uint2 pk;
        pk.x = (unsigned int)f2bf(v0) | ((unsigned int)f2bf(v1) << 16);
        pk.y = (unsigned int)f2bf(v2) | ((unsigned int)f2bf(v3) << 16);
        *(uint2*)(outb + (size_t)row*768 + c4) = pk;
      } else if constexpr (EPI == 1){
        int w = row / 98, n = row % 98;
        int b = w >> 9, rr = w & 511;
        int di = rr >> 6, hi = (rr >> 3) & 7, wi = rr & 7;
        int d2 = n / 49, n2 = n % 49, h2 = n2 / 7, w2 = n2 % 7;
        int sd = (di*2 + d2 + 1) & 15;
        int sh = hi*7 + h2 + 3; if (sh >= 56) sh -= 56;
        int sw = wi*7 + w2 + 3; if (sw >= 56) sw -= 56;
        size_t tnat = (((size_t)b*16 + sd)*56 + sh)*56 + sw;
        float4 xr = *(const float4*)(xres + tnat*256 + c4);
        float4 ov;
        ov.x = xr.x + v0; ov.y = xr.y + v1; ov.z = xr.z + v2; ov.w = xr.w + v3;
        *(float4*)(outf + tnat*256 + c4) = ov;
      } else if constexpr (EPI == 2){
        float g0 = v0 * 0.5f * (1.f + erff(v0 * 0.70710678118654752f));
        float g1 = v1 * 0.5f * (1.f + erff(v1 * 0.70710678118654752f));
        float g2 = v2 * 0.5f * (1.f + erff(v2 * 0.70710678118654752f));
        float g3 = v3 * 0.5f * (1.f + erff(v3 * 0.70710678118654752f));
        uint2 pk;
        pk.x = (unsigned int)f2bf(g0) | ((unsigned int)f2bf(g1) << 16);
        pk.y = (unsigned int)f2bf(g2) | ((unsigned int)f2bf(g3) << 16);
        *(uint2*)(outb + (size_t)row*1024 + c4) = pk;
      } else {
        float* p = outf + (size_t)(moff + row)*256 + c4;
        float4 cu = *(const float4*)p;
        cu.x += v0; cu.y += v1; cu.z += v2; cu.w += v3;
        *(float4*)p = cu;
      }
    }
  }
}

// ---------------- fused window attention ----------------
// One WAVE owns one (window, head), iterates all 7 m-tiles. K/V fragments hoisted
// to registers; combo enters as MFMA C-init; tile-wide softmax max; row sums via a
// 3rd MFMA accumulator (all-ones B); normalization deferred to the epilogue.
__launch_bounds__(256)
__global__ void attnk(const unsigned short* __restrict__ qkv, const unsigned short* __restrict__ comboX,
                      unsigned short* __restrict__ obuf)
{
  __shared__ unsigned short P[4][16*136];   // stride 136 breaks the 256B-stride bank conflict
  int tid = threadIdx.x, wid = tid >> 6, lane = tid & 63, l16 = lane & 15, lk = lane >> 4;
  int cpx = gridDim.x >> 3;
  int swb = (blockIdx.x & 7)*cpx + (blockIdx.x >> 3);
  int task = swb*4 + wid;                   // 2048 blocks * 4 waves = 8192 (w,h) tasks
  int w = task >> 3, h = task & 7;
  int rr = w & 511;
  int pat = (((rr>>6)==7)?4:0) | ((((rr>>3)&7)==7)?2:0) | (((rr&7)==7)?1:0);
  const unsigned short* cb = comboX + (size_t)(pat*8 + h)*12544;   // 7mt*7nt*256
  const unsigned short* base = qkv + (size_t)w*98*768 + h*32;      // q cols; k +256; v +512

  // K fragments once per wave (mt-invariant)
  bf16x8 kfr[7];
  #pragma unroll
  for (int nt = 0; nt < 7; nt++){
    int kc = nt*16 + l16; if (kc > 97) kc = 97;
    kfr[nt] = *(const bf16x8*)(base + (size_t)kc*768 + 256 + lk*8);
  }
  // V fragments (transposed gather, e-pair order) once per wave
  bf16x8 v0[4], v1[4];
  #pragma unroll
  for (int kcc = 0; kcc < 4; kcc++){
    #pragma unroll
    for (int j = 0; j < 8; j++){
      int k = kcc*32 + lk*8 + j; if (k > 97) k = 97;   // P is zero past col 97
      unsigned int u = *(const unsigned int*)(base + (size_t)k*768 + 512 + 2*l16);
      v0[kcc][j] = (short)(u & 0xffff);
      v1[kcc][j] = (short)(u >> 16);
    }
  }
  bf16x8 vones;
  #pragma unroll
  for (int j = 0; j < 8; j++) vones[j] = (short)0x3F80;   // bf16 1.0

  unsigned short* Pw = &P[wid][0];
  { int rp = lane >> 2, cc = 112 + (lane & 3)*4;
    *(uint2*)&Pw[rp*136 + cc] = make_uint2(0u, 0u); }   // zero pad cols 112..127 (never rewritten)

  for (int mt = 0; mt < 7; mt++){
    int qrow = mt*16 + l16; if (qrow > 97) qrow = 97;
    bf16x8 qa = *(const bf16x8*)(base + (size_t)qrow*768 + lk*8);

    const unsigned short* cm = cb + mt*1792;
    f32x4 s[7];
    #pragma unroll
    for (int nt = 0; nt < 7; nt++){
      uint2 c2 = *(const uint2*)(cm + (nt*64 + lane)*4);
      f32x4 ci;
      ci[0] = __uint_as_float(c2.x << 16);
      ci[1] = __uint_as_float(c2.x & 0xffff0000u);
      ci[2] = __uint_as_float(c2.y << 16);
      ci[3] = __uint_as_float(c2.y & 0xffff0000u);
      s[nt] = __builtin_amdgcn_mfma_f32_16x16x32_bf16(qa, kfr[nt], ci, 0, 0, 0);
    }

    float mx[4] = {-3e38f,-3e38f,-3e38f,-3e38f};
    #pragma unroll
    for (int nt = 0; nt < 7; nt++){
      mx[0] = fmaxf(mx[0], s[nt][0]); mx[1] = fmaxf(mx[1], s[nt][1]);
      mx[2] = fmaxf(mx[2], s[nt][2]); mx[3] = fmaxf(mx[3], s[nt][3]);
    }
    float mxa = fmaxf(fmaxf(mx[0], mx[1]), fmaxf(mx[2], mx[3]));
    #pragma unroll
    for (int off = 1; off < 64; off <<= 1) mxa = fmaxf(mxa, __shfl_xor(mxa, off));

    #pragma unroll
    for (int r = 0; r < 4; r++)
      #pragma unroll
      for (int nt = 0; nt < 7; nt++)
        Pw[(lk*4 + r)*136 + nt*16 + l16] = f2bf(__expf(s[nt][r] - mxa));

    f32x4 o0 = (f32x4){0.f,0.f,0.f,0.f}, o1 = (f32x4){0.f,0.f,0.f,0.f};
    f32x4 os = (f32x4){0.f,0.f,0.f,0.f};
    #pragma unroll
    for (int kcc = 0; kcc < 4; kcc++){
      bf16x8 pa = *(const bf16x8*)&Pw[l16*136 + kcc*32 + lk*8];
      __builtin_amdgcn_s_setprio(1);
      o0 = __builtin_amdgcn_mfma_f32_16x16x32_bf16(pa, v0[kcc], o0, 0, 0, 0);
      o1 = __builtin_amdgcn_mfma_f32_16x16x32_bf16(pa, v1[kcc], o1, 0, 0, 0);
      os = __builtin_amdgcn_mfma_f32_16x16x32_bf16(pa, vones,   os, 0, 0, 0);
      __builtin_amdgcn_s_setprio(0);
    }
    #pragma unroll
    for (int r = 0; r < 4; r++){
      int n = mt*16 + lk*4 + r;
      if (n < 98){
        float inv = __builtin_amdgcn_rcpf(os[r]);
        unsigned int pk = (unsigned int)f2bf(o0[r]*inv) | ((unsigned int)f2bf(o1[r]*inv) << 16);
        *(unsigned int*)(obuf + ((size_t)w*98 + n)*256 + h*32 + 2*l16) = pk;
      }
    }
  }
}

extern "C" void kernel_launch(void* const* d_in, const int* in_sizes, int n_in,
                              void* d_out, int out_size, void* d_ws, size_t ws_size,
                              hipStream_t stream)
{
  const float* x     = (const float*)d_in[0];
  const float* maskm = (const float*)d_in[1];
  const int*   ri    = (const int*)d_in[2];
  const float* tbl   = (const float*)d_in[3];
  const float* n1w   = (const float*)d_in[4];
  const float* n1b   = (const float*)d_in[5];
  const float* qkvw  = (const float*)d_in[6];
  const float* qkvbv = (const float*)d_in[7];
  const float* projw = (const float*)d_in[8];
  const float* projb = (const float*)d_in[9];
  const float* n2w   = (const float*)d_in[10];
  const float* n2b   = (const float*)d_in[11];
  const float* fc1w  = (const float*)d_in[12];
  const float* fc1b  = (const float*)d_in[13];
  const float* fc2w  = (const float*)d_in[14];
  const float* fc2b  = (const float*)d_in[15];
  float* dout = (float*)d_out;
  char* ws = (char*)d_ws;

  // ---- part-1 layout (peak 207.52 MB) ----
  unsigned short* qkvB  = (unsigned short*)(ws + 0);           // 100352*768 bf16 = 154,140,672 B
  unsigned short* hb    = (unsigned short*)(ws + 154140672);   // 100352*256 bf16 (LN1 out, then attn out)
  unsigned short* wq    = (unsigned short*)(ws + 205520896);   // 768*256 bf16
  unsigned short* comboX= (unsigned short*)(ws + 205914112);   // 802816 bf16 = 1,605,632 B
  // ---- after attnk (dead qkvB region) ----
  unsigned short* wp = (unsigned short*)(ws + 0);              // 256*256 bf16 (128 KB)
  unsigned short* w1 = (unsigned short*)(ws + 131072);         // 1024*256 bf16 (512 KB)
  unsigned short* w2 = (unsigned short*)(ws + 655360);         // 256*1024 bf16 (512 KB)
  unsigned short* h2 = (unsigned short*)(ws + 2097152);        // 100352*256 bf16 -> end 53,477,376
  unsigned short* g  = (unsigned short*)(ws + 53477376);       // 50176*1024 bf16 -> end 156,237,824 (hb dead by then)

  prepk<<<3904, 256, 0, stream>>>(qkvw, wq, ri, tbl, maskm, comboX);    // wq cast + combo build

  lnk<<<25088, 256, 0, stream>>>(x, n1w, n1b, hb, 0);                                      // LN1+shift+window
  gemmk<0><<<784*6, 256, 0, stream>>>(hb, wq, qkvbv, 256, 6, qkvB, nullptr, nullptr, 0);   // qkv
  attnk<<<2048, 256, 0, stream>>>(qkvB, comboX, hb);                                       // attention
  cvtk<<<256, 256, 0, stream>>>(projw, wp, 65536);                                         // into dead q space
  cvt2k<<<2048, 256, 0, stream>>>(fc1w, 262144, fc2w, 262144, w1);                         // w1+w2
  gemmk<1><<<784*2, 256, 0, stream>>>(hb, wp, projb, 256, 2, nullptr, x, dout, 0);         // proj+residual

  lnk<<<25088, 256, 0, stream>>>(dout, n2w, n2b, h2, 1);                                   // LN2
  for (int c = 0; c < 2; c++){
    gemmk<2><<<392*8, 256, 0, stream>>>(h2 + (size_t)c*50176*256, w1, fc1b, 256, 8, g, nullptr, nullptr, 0);
    gemmk<3><<<392*2, 256, 0, stream>>>(g, w2, fc2b, 1024, 2, nullptr, nullptr, dout, c*50176);
  }
}

// Round 14
// 479.408 us; speedup vs baseline: 1.0569x; 1.0569x over previous
//
#include <hip/hip_runtime.h>
#include <hip/hip_bf16.h>

typedef __attribute__((ext_vector_type(8))) short bf16x8;
typedef __attribute__((ext_vector_type(4))) float f32x4;

__device__ __forceinline__ unsigned short f2bf(float f){
  __hip_bfloat16 h = __float2bfloat16(f);
  return *reinterpret_cast<unsigned short*>(&h);
}

// GELU via tanh/sigmoid approximation: 0.5x(1+tanh(0.79788456(x+0.044715x^3)))
// = x * sigmoid(1.59576912(x+0.044715x^3)); max abs err ~3e-4 (threshold 0.114).
__device__ __forceinline__ float gelu_fast(float x){
  float z = -1.5957691216057308f * (x + 0.044715f * x*x*x);
  return x * __builtin_amdgcn_rcpf(1.f + __expf(z));
}

#define GLDS16(gptr, lptr) \
  __builtin_amdgcn_global_load_lds((const __attribute__((address_space(1))) unsigned int*)(gptr), \
                                   (__attribute__((address_space(3))) unsigned int*)(lptr), 16, 0, 0)

// ---------------- merged prep: qkv weight cast (blocks 0..767) + combo build (768..3903) ----------------
__global__ void prepk(const float* __restrict__ qkvw, unsigned short* __restrict__ wq,
                      const int* __restrict__ ri, const float* __restrict__ tbl,
                      const float* __restrict__ mask, unsigned short* __restrict__ combo){
  int blk = blockIdx.x;
  if (blk < 768){
    int i = blk*256 + threadIdx.x;
    wq[i] = f2bf(qkvw[i]);
    return;
  }
  int g = (blk - 768)*256 + threadIdx.x;
  if (g >= 802816) return;
  int r = g & 3;
  int t = g >> 2;
  int lane = t & 63; t >>= 6;
  int nt = t % 7; t /= 7;
  int mt = t % 7; t /= 7;
  int p = t >> 3, h = t & 7;
  int gi = mt*16 + (lane >> 4)*4 + r; if (gi > 97) gi = 97;
  int j  = nt*16 + (lane & 15);
  float v;
  if (j < 98){
    int wrep = ((p&4)?448:0) + ((p&2)?56:0) + ((p&1)?7:0);
    v = tbl[ri[gi*98 + j]*8 + h] + mask[(size_t)wrep*9604 + gi*98 + j];
  } else {
    v = -30000.f;
  }
  combo[g] = f2bf(v);
}

// two-source conversion (w1 then w2 into adjacent dests)
__global__ void cvt2k(const float* __restrict__ s1, int n1, const float* __restrict__ s2, int n2,
                      unsigned short* __restrict__ d){
  int i = blockIdx.x*256 + threadIdx.x;
  if (i < n1) d[i] = f2bf(s1[i]);
  else if (i < n1 + n2) d[i] = f2bf(s2[i - n1]);
}

__global__ void cvtk(const float* __restrict__ s, unsigned short* __restrict__ d, int n){
  int i = blockIdx.x*256 + threadIdx.x;
  if (i < n) d[i] = f2bf(s[i]);
}

// ---------------- LayerNorm (+optional shift/window map) ----------------
__launch_bounds__(256)
__global__ void lnk(const float* __restrict__ xin, const float* __restrict__ gw, const float* __restrict__ gb,
                    unsigned short* __restrict__ hout, int mode)
{
  int wid = threadIdx.x >> 6, lane = threadIdx.x & 63;
  int tok = blockIdx.x*4 + wid;
  int src;
  if (mode == 0){
    int w = tok / 98, n = tok % 98;
    int b = w >> 9, rr = w & 511;
    int di = rr >> 6, hi = (rr >> 3) & 7, wi = rr & 7;
    int d2 = n / 49, n2 = n % 49, h2 = n2 / 7, w2 = n2 % 7;
    int sd = (di*2 + d2 + 1) & 15;
    int sh = hi*7 + h2 + 3; if (sh >= 56) sh -= 56;
    int sw = wi*7 + w2 + 3; if (sw >= 56) sw -= 56;
    src = ((b*16 + sd)*56 + sh)*56 + sw;
  } else {
    src = tok;
  }
  float4 v = *(const float4*)(xin + (size_t)src*256 + lane*4);
  float s  = v.x + v.y + v.z + v.w;
  float s2 = v.x*v.x + v.y*v.y + v.z*v.z + v.w*v.w;
  #pragma unroll
  for (int off = 1; off < 64; off <<= 1){
    s  += __shfl_xor(s, off);
    s2 += __shfl_xor(s2, off);
  }
  float mean = s * (1.f/256.f);
  float var  = s2 * (1.f/256.f) - mean*mean;
  float rstd = rsqrtf(var + 1e-5f);
  int c = lane*4;
  float4 wv = *(const float4*)(gw + c);
  float4 bv = *(const float4*)(gb + c);
  unsigned int p0 = (unsigned int)f2bf((v.x-mean)*rstd*wv.x + bv.x)
                  | ((unsigned int)f2bf((v.y-mean)*rstd*wv.y + bv.y) << 16);
  unsigned int p1 = (unsigned int)f2bf((v.z-mean)*rstd*wv.z + bv.z)
                  | ((unsigned int)f2bf((v.w-mean)*rstd*wv.w + bv.w) << 16);
  uint2 pk; pk.x = p0; pk.y = p1;
  *(uint2*)(hout + (size_t)tok*256 + c) = pk;
}

// ---------------- bf16 MFMA GEMM: C[M,N] = A[M,K] * Bw[N,K]^T + bias ----------------
// Round-12 proven config: XCD-chunked bijective block swizzle; T2 LDS XOR-swizzle;
// 2-phase dbuf with COUNTED vmcnt (raw s_barrier, never drain to 0 mid-loop).
// B-row permutation -> each lane's 4 ni-values are 4 CONSECUTIVE output columns.
// NOTE: launch_bounds (256,4); (256,5) spilled (r11); tri-buffer lost occupancy (r13).
// EPI 0: qkv plain [row][768] (+q scale on cols<256)
// EPI 1: proj + unwindow/unroll + residual
// EPI 2: fc1 + fast-GELU -> bf16           EPI 3: fc2 accumulate into d_out
template<int EPI>
__launch_bounds__(256, 4)
__global__ void gemmk(const unsigned short* __restrict__ A, const unsigned short* __restrict__ Bw,
                      const float* __restrict__ bias, int K, int nbx,
                      unsigned short* __restrict__ outb, const float* __restrict__ xres,
                      float* __restrict__ outf, int moff)
{
  __shared__ unsigned short As[2][4096];
  __shared__ unsigned short Bs[2][4096];
  int tid = threadIdx.x;
  int wid = tid >> 6, lane = tid & 63, l16 = lane & 15, lk = lane >> 4;
  int wm = wid >> 1, wn = wid & 1;
  int cpx = gridDim.x >> 3;
  int swb = (blockIdx.x & 7)*cpx + (blockIdx.x >> 3);
  int mblk = swb / nbx, nblk = swb % nbx;
  const unsigned short* Ab = A  + (size_t)mblk*128*K;
  const unsigned short* Bb = Bw + (size_t)nblk*128*K;
  int rA = tid >> 2;
  int rB = ((rA & 15) << 2) + ((rA >> 4) & 3);    // B-row permutation (within 64-half)
  int kcA = (((tid & 3) ^ ((tid >> 3) & 3)))*8;   // pre-swizzled global k-slot
  int sx = (l16 >> 1) & 3;                        // read-side XOR factor

#define STAGE(bufi, kss) do { \
    GLDS16(Ab + (size_t)rA*K      + (kss) + kcA, &As[bufi][wid*512]); \
    GLDS16(Ab + (size_t)(rA+64)*K + (kss) + kcA, &As[bufi][2048 + wid*512]); \
    GLDS16(Bb + (size_t)rB*K      + (kss) + kcA, &Bs[bufi][wid*512]); \
    GLDS16(Bb + (size_t)(rB+64)*K + (kss) + kcA, &Bs[bufi][2048 + wid*512]); \
  } while(0)

  f32x4 acc[4][4];
  #pragma unroll
  for (int i = 0; i < 4; i++)
    #pragma unroll
    for (int j = 0; j < 4; j++)
      acc[i][j] = (f32x4){0.f,0.f,0.f,0.f};

  STAGE(0, 0);
  int cur = 0;
  for (int ks = 0; ks < K; ks += 32){
    if (ks + 32 < K){
      STAGE(cur ^ 1, ks + 32);                       // prefetch next tile (4 loads)
      asm volatile("s_waitcnt vmcnt(4)" ::: "memory"); // wait ONLY cur tile's loads
    } else {
      asm volatile("s_waitcnt vmcnt(0)" ::: "memory");
    }
    __builtin_amdgcn_s_barrier();
    __builtin_amdgcn_sched_barrier(0);
    bf16x8 af[4], bfr[4];
    #pragma unroll
    for (int mi = 0; mi < 4; mi++) af[mi]  = *(const bf16x8*)&As[cur][(wm*64 + mi*16 + l16)*32 + (lk ^ sx)*8];
    #pragma unroll
    for (int ni = 0; ni < 4; ni++) bfr[ni] = *(const bf16x8*)&Bs[cur][(wn*64 + ni*16 + l16)*32 + (lk ^ sx)*8];
    #pragma unroll
    for (int mi = 0; mi < 4; mi++)
      #pragma unroll
      for (int ni = 0; ni < 4; ni++)
        acc[mi][ni] = __builtin_amdgcn_mfma_f32_16x16x32_bf16(af[mi], bfr[ni], acc[mi][ni], 0, 0, 0);
    __builtin_amdgcn_sched_barrier(0);
    __builtin_amdgcn_s_barrier();
    cur ^= 1;
  }
#undef STAGE

  int rowb = mblk*128 + wm*64;
  int colb = nblk*128 + wn*64;
  int c4 = colb + 4*l16;                 // this lane's 4 consecutive output columns
  float4 bv = *(const float4*)(bias + c4);
  #pragma unroll
  for (int mi = 0; mi < 4; mi++){
    #pragma unroll
    for (int r = 0; r < 4; r++){
      int row = rowb + mi*16 + lk*4 + r;
      float v0 = acc[mi][0][r] + bv.x;
      float v1 = acc[mi][1][r] + bv.y;
      float v2 = acc[mi][2][r] + bv.z;
      float v3 = acc[mi][3][r] + bv.w;
      if constexpr (EPI == 0){
        if (colb < 256){
          const float sc = 0.17677669529663687f;
          v0 *= sc; v1 *= sc; v2 *= sc; v3 *= sc;
        }
        uint2 pk;
        pk.x = (unsigned int)f2bf(v0) | ((unsigned int)f2bf(v1) << 16);
        pk.y = (unsigned int)f2bf(v2) | ((unsigned int)f2bf(v3) << 16);
        *(uint2*)(outb + (size_t)row*768 + c4) = pk;
      } else if constexpr (EPI == 1){
        int w = row / 98, n = row % 98;
        int b = w >> 9, rr = w & 511;
        int di = rr >> 6, hi = (rr >> 3) & 7, wi = rr & 7;
        int d2 = n / 49, n2 = n % 49, h2 = n2 / 7, w2 = n2 % 7;
        int sd = (di*2 + d2 + 1) & 15;
        int sh = hi*7 + h2 + 3; if (sh >= 56) sh -= 56;
        int sw = wi*7 + w2 + 3; if (sw >= 56) sw -= 56;
        size_t tnat = (((size_t)b*16 + sd)*56 + sh)*56 + sw;
        float4 xr = *(const float4*)(xres + tnat*256 + c4);
        float4 ov;
        ov.x = xr.x + v0; ov.y = xr.y + v1; ov.z = xr.z + v2; ov.w = xr.w + v3;
        *(float4*)(outf + tnat*256 + c4) = ov;
      } else if constexpr (EPI == 2){
        float g0 = gelu_fast(v0);
        float g1 = gelu_fast(v1);
        float g2 = gelu_fast(v2);
        float g3 = gelu_fast(v3);
        uint2 pk;
        pk.x = (unsigned int)f2bf(g0) | ((unsigned int)f2bf(g1) << 16);
        pk.y = (unsigned int)f2bf(g2) | ((unsigned int)f2bf(g3) << 16);
        *(uint2*)(outb + (size_t)row*1024 + c4) = pk;
      } else {
        float* p = outf + (size_t)(moff + row)*256 + c4;
        float4 cu = *(const float4*)p;
        cu.x += v0; cu.y += v1; cu.z += v2; cu.w += v3;
        *(float4*)p = cu;
      }
    }
  }
}

// ---------------- fused window attention ----------------
// One WAVE owns one (window, head), iterates all 7 m-tiles. K/V fragments hoisted
// to registers; combo enters as MFMA C-init; NO max-pass softmax (logits bounded
// ~±3 for this data: LN'd inputs x 0.02-std weights; masked entries ~-100 -> exp->0;
// clamp at 60 as overflow insurance: exp(60)*98 << fp32 max). Row sums via a 3rd
// MFMA accumulator (all-ones B); normalization deferred to the epilogue.
__launch_bounds__(256)
__global__ void attnk(const unsigned short* __restrict__ qkv, const unsigned short* __restrict__ comboX,
                      unsigned short* __restrict__ obuf)
{
  __shared__ unsigned short P[4][16*136];   // stride 136 breaks the 256B-stride bank conflict
  int tid = threadIdx.x, wid = tid >> 6, lane = tid & 63, l16 = lane & 15, lk = lane >> 4;
  int cpx = gridDim.x >> 3;
  int swb = (blockIdx.x & 7)*cpx + (blockIdx.x >> 3);
  int task = swb*4 + wid;                   // 2048 blocks * 4 waves = 8192 (w,h) tasks
  int w = task >> 3, h = task & 7;
  int rr = w & 511;
  int pat = (((rr>>6)==7)?4:0) | ((((rr>>3)&7)==7)?2:0) | (((rr&7)==7)?1:0);
  const unsigned short* cb = comboX + (size_t)(pat*8 + h)*12544;   // 7mt*7nt*256
  const unsigned short* base = qkv + (size_t)w*98*768 + h*32;      // q cols; k +256; v +512

  // K fragments once per wave (mt-invariant)
  bf16x8 kfr[7];
  #pragma unroll
  for (int nt = 0; nt < 7; nt++){
    int kc = nt*16 + l16; if (kc > 97) kc = 97;
    kfr[nt] = *(const bf16x8*)(base + (size_t)kc*768 + 256 + lk*8);
  }
  // V fragments (transposed gather, e-pair order) once per wave
  bf16x8 v0[4], v1[4];
  #pragma unroll
  for (int kcc = 0; kcc < 4; kcc++){
    #pragma unroll
    for (int j = 0; j < 8; j++){
      int k = kcc*32 + lk*8 + j; if (k > 97) k = 97;   // P is zero past col 97
      unsigned int u = *(const unsigned int*)(base + (size_t)k*768 + 512 + 2*l16);
      v0[kcc][j] = (short)(u & 0xffff);
      v1[kcc][j] = (short)(u >> 16);
    }
  }
  bf16x8 vones;
  #pragma unroll
  for (int j = 0; j < 8; j++) vones[j] = (short)0x3F80;   // bf16 1.0

  unsigned short* Pw = &P[wid][0];
  { int rp = lane >> 2, cc = 112 + (lane & 3)*4;
    *(uint2*)&Pw[rp*136 + cc] = make_uint2(0u, 0u); }   // zero pad cols 112..127 (never rewritten)

  for (int mt = 0; mt < 7; mt++){
    int qrow = mt*16 + l16; if (qrow > 97) qrow = 97;
    bf16x8 qa = *(const bf16x8*)(base + (size_t)qrow*768 + lk*8);

    const unsigned short* cm = cb + mt*1792;
    f32x4 s[7];
    #pragma unroll
    for (int nt = 0; nt < 7; nt++){
      uint2 c2 = *(const uint2*)(cm + (nt*64 + lane)*4);
      f32x4 ci;
      ci[0] = __uint_as_float(c2.x << 16);
      ci[1] = __uint_as_float(c2.x & 0xffff0000u);
      ci[2] = __uint_as_float(c2.y << 16);
      ci[3] = __uint_as_float(c2.y & 0xffff0000u);
      s[nt] = __builtin_amdgcn_mfma_f32_16x16x32_bf16(qa, kfr[nt], ci, 0, 0, 0);
    }

    // exp without max-subtraction (bounded logits; clamp for insurance)
    #pragma unroll
    for (int r = 0; r < 4; r++)
      #pragma unroll
      for (int nt = 0; nt < 7; nt++)
        Pw[(lk*4 + r)*136 + nt*16 + l16] = f2bf(__expf(fminf(s[nt][r], 60.f)));

    f32x4 o0 = (f32x4){0.f,0.f,0.f,0.f}, o1 = (f32x4){0.f,0.f,0.f,0.f};
    f32x4 os = (f32x4){0.f,0.f,0.f,0.f};
    #pragma unroll
    for (int kcc = 0; kcc < 4; kcc++){
      bf16x8 pa = *(const bf16x8*)&Pw[l16*136 + kcc*32 + lk*8];
      __builtin_amdgcn_s_setprio(1);
      o0 = __builtin_amdgcn_mfma_f32_16x16x32_bf16(pa, v0[kcc], o0, 0, 0, 0);
      o1 = __builtin_amdgcn_mfma_f32_16x16x32_bf16(pa, v1[kcc], o1, 0, 0, 0);
      os = __builtin_amdgcn_mfma_f32_16x16x32_bf16(pa, vones,   os, 0, 0, 0);
      __builtin_amdgcn_s_setprio(0);
    }
    #pragma unroll
    for (int r = 0; r < 4; r++){
      int n = mt*16 + lk*4 + r;
      if (n < 98){
        float inv = __builtin_amdgcn_rcpf(os[r]);
        unsigned int pk = (unsigned int)f2bf(o0[r]*inv) | ((unsigned int)f2bf(o1[r]*inv) << 16);
        *(unsigned int*)(obuf + ((size_t)w*98 + n)*256 + h*32 + 2*l16) = pk;
      }
    }
  }
}

extern "C" void kernel_launch(void* const* d_in, const int* in_sizes, int n_in,
                              void* d_out, int out_size, void* d_ws, size_t ws_size,
                              hipStream_t stream)
{
  const float* x     = (const float*)d_in[0];
  const float* maskm = (const float*)d_in[1];
  const int*   ri    = (const int*)d_in[2];
  const float* tbl   = (const float*)d_in[3];
  const float* n1w   = (const float*)d_in[4];
  const float* n1b   = (const float*)d_in[5];
  const float* qkvw  = (const float*)d_in[6];
  const float* qkvbv = (const float*)d_in[7];
  const float* projw = (const float*)d_in[8];
  const float* projb = (const float*)d_in[9];
  const float* n2w   = (const float*)d_in[10];
  const float* n2b   = (const float*)d_in[11];
  const float* fc1w  = (const float*)d_in[12];
  const float* fc1b  = (const float*)d_in[13];
  const float* fc2w  = (const float*)d_in[14];
  const float* fc2b  = (const float*)d_in[15];
  float* dout = (float*)d_out;
  char* ws = (char*)d_ws;

  // ---- part-1 layout (peak 207.52 MB) ----
  unsigned short* qkvB  = (unsigned short*)(ws + 0);           // 100352*768 bf16 = 154,140,672 B
  unsigned short* hb    = (unsigned short*)(ws + 154140672);   // 100352*256 bf16 (LN1 out, then attn out)
  unsigned short* wq    = (unsigned short*)(ws + 205520896);   // 768*256 bf16
  unsigned short* comboX= (unsigned short*)(ws + 205914112);   // 802816 bf16 = 1,605,632 B
  // ---- after attnk (dead qkvB region) ----
  unsigned short* wp = (unsigned short*)(ws + 0);              // 256*256 bf16 (128 KB)
  unsigned short* w1 = (unsigned short*)(ws + 131072);         // 1024*256 bf16 (512 KB)
  unsigned short* w2 = (unsigned short*)(ws + 655360);         // 256*1024 bf16 (512 KB)
  unsigned short* h2 = (unsigned short*)(ws + 2097152);        // 100352*256 bf16 -> end 53,477,376
  unsigned short* g  = (unsigned short*)(ws + 53477376);       // 50176*1024 bf16 -> end 156,237,824 (hb dead by then)

  prepk<<<3904, 256, 0, stream>>>(qkvw, wq, ri, tbl, maskm, comboX);    // wq cast + combo build

  lnk<<<25088, 256, 0, stream>>>(x, n1w, n1b, hb, 0);                                      // LN1+shift+window
  gemmk<0><<<784*6, 256, 0, stream>>>(hb, wq, qkvbv, 256, 6, qkvB, nullptr, nullptr, 0);   // qkv
  attnk<<<2048, 256, 0, stream>>>(qkvB, comboX, hb);                                       // attention
  cvtk<<<256, 256, 0, stream>>>(projw, wp, 65536);                                         // into dead q space
  cvt2k<<<2048, 256, 0, stream>>>(fc1w, 262144, fc2w, 262144, w1);                         // w1+w2
  gemmk<1><<<784*2, 256, 0, stream>>>(hb, wp, projb, 256, 2, nullptr, x, dout, 0);         // proj+residual

  lnk<<<25088, 256, 0, stream>>>(dout, n2w, n2b, h2, 1);                                   // LN2
  for (int c = 0; c < 2; c++){
    gemmk<2><<<392*8, 256, 0, stream>>>(h2 + (size_t)c*50176*256, w1, fc1b, 256, 8, g, nullptr, nullptr, 0);
    gemmk<3><<<392*2, 256, 0, stream>>>(g, w2, fc2b, 1024, 2, nullptr, nullptr, dout, c*50176);
  }
}

// Round 15
// 459.595 us; speedup vs baseline: 1.1025x; 1.0431x over previous
//
#include <hip/hip_runtime.h>
#include <hip/hip_bf16.h>

typedef __attribute__((ext_vector_type(8))) short bf16x8;
typedef __attribute__((ext_vector_type(4))) float f32x4;

__device__ __forceinline__ unsigned short f2bf(float f){
  __hip_bfloat16 h = __float2bfloat16(f);
  return *reinterpret_cast<unsigned short*>(&h);
}

// GELU via tanh/sigmoid approximation: 0.5x(1+tanh(0.79788456(x+0.044715x^3)))
// = x * sigmoid(1.59576912(x+0.044715x^3)); max abs err ~3e-4 (threshold 0.114).
__device__ __forceinline__ float gelu_fast(float x){
  float z = -1.5957691216057308f * (x + 0.044715f * x*x*x);
  return x * __builtin_amdgcn_rcpf(1.f + __expf(z));
}

#define GLDS16(gptr, lptr) \
  __builtin_amdgcn_global_load_lds((const __attribute__((address_space(1))) unsigned int*)(gptr), \
                                   (__attribute__((address_space(3))) unsigned int*)(lptr), 16, 0, 0)

// ---------------- merged prep: qkv weight cast (blocks 0..767) + combo build (768..3903) ----------------
__global__ void prepk(const float* __restrict__ qkvw, unsigned short* __restrict__ wq,
                      const int* __restrict__ ri, const float* __restrict__ tbl,
                      const float* __restrict__ mask, unsigned short* __restrict__ combo){
  int blk = blockIdx.x;
  if (blk < 768){
    int i = blk*256 + threadIdx.x;
    wq[i] = f2bf(qkvw[i]);
    return;
  }
  int g = (blk - 768)*256 + threadIdx.x;
  if (g >= 802816) return;
  int r = g & 3;
  int t = g >> 2;
  int lane = t & 63; t >>= 6;
  int nt = t % 7; t /= 7;
  int mt = t % 7; t /= 7;
  int p = t >> 3, h = t & 7;
  int gi = mt*16 + (lane >> 4)*4 + r; if (gi > 97) gi = 97;
  int j  = nt*16 + (lane & 15);
  float v;
  if (j < 98){
    int wrep = ((p&4)?448:0) + ((p&2)?56:0) + ((p&1)?7:0);
    v = tbl[ri[gi*98 + j]*8 + h] + mask[(size_t)wrep*9604 + gi*98 + j];
  } else {
    v = -30000.f;
  }
  combo[g] = f2bf(v);
}

// two-source conversion (w1 then w2 into adjacent dests)
__global__ void cvt2k(const float* __restrict__ s1, int n1, const float* __restrict__ s2, int n2,
                      unsigned short* __restrict__ d){
  int i = blockIdx.x*256 + threadIdx.x;
  if (i < n1) d[i] = f2bf(s1[i]);
  else if (i < n1 + n2) d[i] = f2bf(s2[i - n1]);
}

__global__ void cvtk(const float* __restrict__ s, unsigned short* __restrict__ d, int n){
  int i = blockIdx.x*256 + threadIdx.x;
  if (i < n) d[i] = f2bf(s[i]);
}

// ---------------- LayerNorm (+optional shift/window map) ----------------
__launch_bounds__(256)
__global__ void lnk(const float* __restrict__ xin, const float* __restrict__ gw, const float* __restrict__ gb,
                    unsigned short* __restrict__ hout, int mode)
{
  int wid = threadIdx.x >> 6, lane = threadIdx.x & 63;
  int tok = blockIdx.x*4 + wid;
  int src;
  if (mode == 0){
    int w = tok / 98, n = tok % 98;
    int b = w >> 9, rr = w & 511;
    int di = rr >> 6, hi = (rr >> 3) & 7, wi = rr & 7;
    int d2 = n / 49, n2 = n % 49, h2 = n2 / 7, w2 = n2 % 7;
    int sd = (di*2 + d2 + 1) & 15;
    int sh = hi*7 + h2 + 3; if (sh >= 56) sh -= 56;
    int sw = wi*7 + w2 + 3; if (sw >= 56) sw -= 56;
    src = ((b*16 + sd)*56 + sh)*56 + sw;
  } else {
    src = tok;
  }
  float4 v = *(const float4*)(xin + (size_t)src*256 + lane*4);
  float s  = v.x + v.y + v.z + v.w;
  float s2 = v.x*v.x + v.y*v.y + v.z*v.z + v.w*v.w;
  #pragma unroll
  for (int off = 1; off < 64; off <<= 1){
    s  += __shfl_xor(s, off);
    s2 += __shfl_xor(s2, off);
  }
  float mean = s * (1.f/256.f);
  float var  = s2 * (1.f/256.f) - mean*mean;
  float rstd = rsqrtf(var + 1e-5f);
  int c = lane*4;
  float4 wv = *(const float4*)(gw + c);
  float4 bv = *(const float4*)(gb + c);
  unsigned int p0 = (unsigned int)f2bf((v.x-mean)*rstd*wv.x + bv.x)
                  | ((unsigned int)f2bf((v.y-mean)*rstd*wv.y + bv.y) << 16);
  unsigned int p1 = (unsigned int)f2bf((v.z-mean)*rstd*wv.z + bv.z)
                  | ((unsigned int)f2bf((v.w-mean)*rstd*wv.w + bv.w) << 16);
  uint2 pk; pk.x = p0; pk.y = p1;
  *(uint2*)(hout + (size_t)tok*256 + c) = pk;
}

// ---------------- bf16 MFMA GEMM: C[M,N] = A[M,K] * Bw[N,K]^T + bias ----------------
// Round-12 proven config: XCD-chunked bijective block swizzle; T2 LDS XOR-swizzle;
// 2-phase dbuf with COUNTED vmcnt (raw s_barrier, never drain to 0 mid-loop).
// B-row permutation -> each lane's 4 ni-values are 4 CONSECUTIVE output columns.
// NOTE: launch_bounds (256,4); (256,5) spilled (r11); tri-buffer lost occupancy (r13).
// EPI 0: qkv plain [row][768] (+q scale on cols<256)
// EPI 1: proj + unwindow/unroll + residual
// EPI 2: fc1 + fast-GELU -> bf16           EPI 3: fc2 accumulate into d_out
template<int EPI>
__launch_bounds__(256, 4)
__global__ void gemmk(const unsigned short* __restrict__ A, const unsigned short* __restrict__ Bw,
                      const float* __restrict__ bias, int K, int nbx,
                      unsigned short* __restrict__ outb, const float* __restrict__ xres,
                      float* __restrict__ outf, int moff)
{
  __shared__ unsigned short As[2][4096];
  __shared__ unsigned short Bs[2][4096];
  int tid = threadIdx.x;
  int wid = tid >> 6, lane = tid & 63, l16 = lane & 15, lk = lane >> 4;
  int wm = wid >> 1, wn = wid & 1;
  int cpx = gridDim.x >> 3;
  int swb = (blockIdx.x & 7)*cpx + (blockIdx.x >> 3);
  int mblk = swb / nbx, nblk = swb % nbx;
  const unsigned short* Ab = A  + (size_t)mblk*128*K;
  const unsigned short* Bb = Bw + (size_t)nblk*128*K;
  int rA = tid >> 2;
  int rB = ((rA & 15) << 2) + ((rA >> 4) & 3);    // B-row permutation (within 64-half)
  int kcA = (((tid & 3) ^ ((tid >> 3) & 3)))*8;   // pre-swizzled global k-slot
  int sx = (l16 >> 1) & 3;                        // read-side XOR factor

#define STAGE(bufi, kss) do { \
    GLDS16(Ab + (size_t)rA*K      + (kss) + kcA, &As[bufi][wid*512]); \
    GLDS16(Ab + (size_t)(rA+64)*K + (kss) + kcA, &As[bufi][2048 + wid*512]); \
    GLDS16(Bb + (size_t)rB*K      + (kss) + kcA, &Bs[bufi][wid*512]); \
    GLDS16(Bb + (size_t)(rB+64)*K + (kss) + kcA, &Bs[bufi][2048 + wid*512]); \
  } while(0)

  f32x4 acc[4][4];
  #pragma unroll
  for (int i = 0; i < 4; i++)
    #pragma unroll
    for (int j = 0; j < 4; j++)
      acc[i][j] = (f32x4){0.f,0.f,0.f,0.f};

  STAGE(0, 0);
  int cur = 0;
  for (int ks = 0; ks < K; ks += 32){
    if (ks + 32 < K){
      STAGE(cur ^ 1, ks + 32);                       // prefetch next tile (4 loads)
      asm volatile("s_waitcnt vmcnt(4)" ::: "memory"); // wait ONLY cur tile's loads
    } else {
      asm volatile("s_waitcnt vmcnt(0)" ::: "memory");
    }
    __builtin_amdgcn_s_barrier();
    __builtin_amdgcn_sched_barrier(0);
    bf16x8 af[4], bfr[4];
    #pragma unroll
    for (int mi = 0; mi < 4; mi++) af[mi]  = *(const bf16x8*)&As[cur][(wm*64 + mi*16 + l16)*32 + (lk ^ sx)*8];
    #pragma unroll
    for (int ni = 0; ni < 4; ni++) bfr[ni] = *(const bf16x8*)&Bs[cur][(wn*64 + ni*16 + l16)*32 + (lk ^ sx)*8];
    #pragma unroll
    for (int mi = 0; mi < 4; mi++)
      #pragma unroll
      for (int ni = 0; ni < 4; ni++)
        acc[mi][ni] = __builtin_amdgcn_mfma_f32_16x16x32_bf16(af[mi], bfr[ni], acc[mi][ni], 0, 0, 0);
    __builtin_amdgcn_sched_barrier(0);
    __builtin_amdgcn_s_barrier();
    cur ^= 1;
  }
#undef STAGE

  int rowb = mblk*128 + wm*64;
  int colb = nblk*128 + wn*64;
  int c4 = colb + 4*l16;                 // this lane's 4 consecutive output columns
  float4 bv = *(const float4*)(bias + c4);
  #pragma unroll
  for (int mi = 0; mi < 4; mi++){
    #pragma unroll
    for (int r = 0; r < 4; r++){
      int row = rowb + mi*16 + lk*4 + r;
      float v0 = acc[mi][0][r] + bv.x;
      float v1 = acc[mi][1][r] + bv.y;
      float v2 = acc[mi][2][r] + bv.z;
      float v3 = acc[mi][3][r] + bv.w;
      if constexpr (EPI == 0){
        if (colb < 256){
          const float sc = 0.17677669529663687f;
          v0 *= sc; v1 *= sc; v2 *= sc; v3 *= sc;
        }
        uint2 pk;
        pk.x = (unsigned int)f2bf(v0) | ((unsigned int)f2bf(v1) << 16);
        pk.y = (unsigned int)f2bf(v2) | ((unsigned int)f2bf(v3) << 16);
        *(uint2*)(outb + (size_t)row*768 + c4) = pk;
      } else if constexpr (EPI == 1){
        int w = row / 98, n = row % 98;
        int b = w >> 9, rr = w & 511;
        int di = rr >> 6, hi = (rr >> 3) & 7, wi = rr & 7;
        int d2 = n / 49, n2 = n % 49, h2 = n2 / 7, w2 = n2 % 7;
        int sd = (di*2 + d2 + 1) & 15;
        int sh = hi*7 + h2 + 3; if (sh >= 56) sh -= 56;
        int sw = wi*7 + w2 + 3; if (sw >= 56) sw -= 56;
        size_t tnat = (((size_t)b*16 + sd)*56 + sh)*56 + sw;
        float4 xr = *(const float4*)(xres + tnat*256 + c4);
        float4 ov;
        ov.x = xr.x + v0; ov.y = xr.y + v1; ov.z = xr.z + v2; ov.w = xr.w + v3;
        *(float4*)(outf + tnat*256 + c4) = ov;
      } else if constexpr (EPI == 2){
        float g0 = gelu_fast(v0);
        float g1 = gelu_fast(v1);
        float g2 = gelu_fast(v2);
        float g3 = gelu_fast(v3);
        uint2 pk;
        pk.x = (unsigned int)f2bf(g0) | ((unsigned int)f2bf(g1) << 16);
        pk.y = (unsigned int)f2bf(g2) | ((unsigned int)f2bf(g3) << 16);
        *(uint2*)(outb + (size_t)row*1024 + c4) = pk;
      } else {
        float* p = outf + (size_t)(moff + row)*256 + c4;
        float4 cu = *(const float4*)p;
        cu.x += v0; cu.y += v1; cu.z += v2; cu.w += v3;
        *(float4*)p = cu;
      }
    }
  }
}

// ---------------- fused window attention (round-12 proven version) ----------------
// One WAVE owns one (window, head), iterates all 7 m-tiles. K/V fragments hoisted
// to registers; combo enters as MFMA C-init; tile-wide softmax max (consumes s[]
// early -> keeps VGPR below the 64-reg occupancy cliff; removing it cost 25 µs in
// r14); row sums via a 3rd MFMA accumulator (all-ones B); normalization deferred.
__launch_bounds__(256)
__global__ void attnk(const unsigned short* __restrict__ qkv, const unsigned short* __restrict__ comboX,
                      unsigned short* __restrict__ obuf)
{
  __shared__ unsigned short P[4][16*136];   // stride 136 breaks the 256B-stride bank conflict
  int tid = threadIdx.x, wid = tid >> 6, lane = tid & 63, l16 = lane & 15, lk = lane >> 4;
  int cpx = gridDim.x >> 3;
  int swb = (blockIdx.x & 7)*cpx + (blockIdx.x >> 3);
  int task = swb*4 + wid;                   // 2048 blocks * 4 waves = 8192 (w,h) tasks
  int w = task >> 3, h = task & 7;
  int rr = w & 511;
  int pat = (((rr>>6)==7)?4:0) | ((((rr>>3)&7)==7)?2:0) | (((rr&7)==7)?1:0);
  const unsigned short* cb = comboX + (size_t)(pat*8 + h)*12544;   // 7mt*7nt*256
  const unsigned short* base = qkv + (size_t)w*98*768 + h*32;      // q cols; k +256; v +512

  // K fragments once per wave (mt-invariant)
  bf16x8 kfr[7];
  #pragma unroll
  for (int nt = 0; nt < 7; nt++){
    int kc = nt*16 + l16; if (kc > 97) kc = 97;
    kfr[nt] = *(const bf16x8*)(base + (size_t)kc*768 + 256 + lk*8);
  }
  // V fragments (transposed gather, e-pair order) once per wave
  bf16x8 v0[4], v1[4];
  #pragma unroll
  for (int kcc = 0; kcc < 4; kcc++){
    #pragma unroll
    for (int j = 0; j < 8; j++){
      int k = kcc*32 + lk*8 + j; if (k > 97) k = 97;   // P is zero past col 97
      unsigned int u = *(const unsigned int*)(base + (size_t)k*768 + 512 + 2*l16);
      v0[kcc][j] = (short)(u & 0xffff);
      v1[kcc][j] = (short)(u >> 16);
    }
  }
  bf16x8 vones;
  #pragma unroll
  for (int j = 0; j < 8; j++) vones[j] = (short)0x3F80;   // bf16 1.0

  unsigned short* Pw = &P[wid][0];
  { int rp = lane >> 2, cc = 112 + (lane & 3)*4;
    *(uint2*)&Pw[rp*136 + cc] = make_uint2(0u, 0u); }   // zero pad cols 112..127 (never rewritten)

  for (int mt = 0; mt < 7; mt++){
    int qrow = mt*16 + l16; if (qrow > 97) qrow = 97;
    bf16x8 qa = *(const bf16x8*)(base + (size_t)qrow*768 + lk*8);

    const unsigned short* cm = cb + mt*1792;
    f32x4 s[7];
    #pragma unroll
    for (int nt = 0; nt < 7; nt++){
      uint2 c2 = *(const uint2*)(cm + (nt*64 + lane)*4);
      f32x4 ci;
      ci[0] = __uint_as_float(c2.x << 16);
      ci[1] = __uint_as_float(c2.x & 0xffff0000u);
      ci[2] = __uint_as_float(c2.y << 16);
      ci[3] = __uint_as_float(c2.y & 0xffff0000u);
      s[nt] = __builtin_amdgcn_mfma_f32_16x16x32_bf16(qa, kfr[nt], ci, 0, 0, 0);
    }

    float mx[4] = {-3e38f,-3e38f,-3e38f,-3e38f};
    #pragma unroll
    for (int nt = 0; nt < 7; nt++){
      mx[0] = fmaxf(mx[0], s[nt][0]); mx[1] = fmaxf(mx[1], s[nt][1]);
      mx[2] = fmaxf(mx[2], s[nt][2]); mx[3] = fmaxf(mx[3], s[nt][3]);
    }
    float mxa = fmaxf(fmaxf(mx[0], mx[1]), fmaxf(mx[2], mx[3]));
    #pragma unroll
    for (int off = 1; off < 64; off <<= 1) mxa = fmaxf(mxa, __shfl_xor(mxa, off));

    #pragma unroll
    for (int r = 0; r < 4; r++)
      #pragma unroll
      for (int nt = 0; nt < 7; nt++)
        Pw[(lk*4 + r)*136 + nt*16 + l16] = f2bf(__expf(s[nt][r] - mxa));

    f32x4 o0 = (f32x4){0.f,0.f,0.f,0.f}, o1 = (f32x4){0.f,0.f,0.f,0.f};
    f32x4 os = (f32x4){0.f,0.f,0.f,0.f};
    #pragma unroll
    for (int kcc = 0; kcc < 4; kcc++){
      bf16x8 pa = *(const bf16x8*)&Pw[l16*136 + kcc*32 + lk*8];
      __builtin_amdgcn_s_setprio(1);
      o0 = __builtin_amdgcn_mfma_f32_16x16x32_bf16(pa, v0[kcc], o0, 0, 0, 0);
      o1 = __builtin_amdgcn_mfma_f32_16x16x32_bf16(pa, v1[kcc], o1, 0, 0, 0);
      os = __builtin_amdgcn_mfma_f32_16x16x32_bf16(pa, vones,   os, 0, 0, 0);
      __builtin_amdgcn_s_setprio(0);
    }
    #pragma unroll
    for (int r = 0; r < 4; r++){
      int n = mt*16 + lk*4 + r;
      if (n < 98){
        float inv = __builtin_amdgcn_rcpf(os[r]);
        unsigned int pk = (unsigned int)f2bf(o0[r]*inv) | ((unsigned int)f2bf(o1[r]*inv) << 16);
        *(unsigned int*)(obuf + ((size_t)w*98 + n)*256 + h*32 + 2*l16) = pk;
      }
    }
  }
}

extern "C" void kernel_launch(void* const* d_in, const int* in_sizes, int n_in,
                              void* d_out, int out_size, void* d_ws, size_t ws_size,
                              hipStream_t stream)
{
  const float* x     = (const float*)d_in[0];
  const float* maskm = (const float*)d_in[1];
  const int*   ri    = (const int*)d_in[2];
  const float* tbl   = (const float*)d_in[3];
  const float* n1w   = (const float*)d_in[4];
  const float* n1b   = (const float*)d_in[5];
  const float* qkvw  = (const float*)d_in[6];
  const float* qkvbv = (const float*)d_in[7];
  const float* projw = (const float*)d_in[8];
  const float* projb = (const float*)d_in[9];
  const float* n2w   = (const float*)d_in[10];
  const float* n2b   = (const float*)d_in[11];
  const float* fc1w  = (const float*)d_in[12];
  const float* fc1b  = (const float*)d_in[13];
  const float* fc2w  = (const float*)d_in[14];
  const float* fc2b  = (const float*)d_in[15];
  float* dout = (float*)d_out;
  char* ws = (char*)d_ws;

  // ---- part-1 layout (peak 207.52 MB) ----
  unsigned short* qkvB  = (unsigned short*)(ws + 0);           // 100352*768 bf16 = 154,140,672 B
  unsigned short* hb    = (unsigned short*)(ws + 154140672);   // 100352*256 bf16 (LN1 out, then attn out)
  unsigned short* wq    = (unsigned short*)(ws + 205520896);   // 768*256 bf16
  unsigned short* comboX= (unsigned short*)(ws + 205914112);   // 802816 bf16 = 1,605,632 B
  // ---- after attnk (dead qkvB region) ----
  unsigned short* wp = (unsigned short*)(ws + 0);              // 256*256 bf16 (128 KB)
  unsigned short* w1 = (unsigned short*)(ws + 131072);         // 1024*256 bf16 (512 KB)
  unsigned short* w2 = (unsigned short*)(ws + 655360);         // 256*1024 bf16 (512 KB)
  unsigned short* h2 = (unsigned short*)(ws + 2097152);        // 100352*256 bf16 -> end 53,477,376
  unsigned short* g  = (unsigned short*)(ws + 53477376);       // 50176*1024 bf16 -> end 156,237,824 (hb dead by then)

  prepk<<<3904, 256, 0, stream>>>(qkvw, wq, ri, tbl, maskm, comboX);    // wq cast + combo build

  lnk<<<25088, 256, 0, stream>>>(x, n1w, n1b, hb, 0);                                      // LN1+shift+window
  gemmk<0><<<784*6, 256, 0, stream>>>(hb, wq, qkvbv, 256, 6, qkvB, nullptr, nullptr, 0);   // qkv
  attnk<<<2048, 256, 0, stream>>>(qkvB, comboX, hb);                                       // attention
  cvtk<<<256, 256, 0, stream>>>(projw, wp, 65536);                                         // into dead q space
  cvt2k<<<2048, 256, 0, stream>>>(fc1w, 262144, fc2w, 262144, w1);                         // w1+w2
  gemmk<1><<<784*2, 256, 0, stream>>>(hb, wp, projb, 256, 2, nullptr, x, dout, 0);         // proj+residual

  lnk<<<25088, 256, 0, stream>>>(dout, n2w, n2b, h2, 1);                                   // LN2
  for (int c = 0; c < 2; c++){
    gemmk<2><<<392*8, 256, 0, stream>>>(h2 + (size_t)c*50176*256, w1, fc1b, 256, 8, g, nullptr, nullptr, 0);
    gemmk<3><<<392*2, 256, 0, stream>>>(g, w2, fc2b, 1024, 2, nullptr, nullptr, dout, c*50176);
  }
}